// Round 11
// baseline (464.222 us; speedup 1.0000x reference)
//
#include <hip/hip_runtime.h>
#include <math.h>

// TAGCN 2-layer GNN on MI355X.
// R11 = R10 + two-pass bucketed CSR build replacing the random scatter:
//   scatter_csr was 42us with 53MB HBM writes (8B random scatters -> one cold
//   64B sector per edge, no L2 merge across XCDs).
//   binA: 4B packed (src<<16|col) appended to bucket (col>>5) regions, cursors
//         = off[b*32] (bucket regions == CSR segment ranges, init in scan3).
//   binB: one block per bucket, LDS atomics over 32 node cursors, computes w,
//         writes final 8B meta into a hot contiguous ~4KB region (full-line
//         evictions).
// Also: wtrans x2 + x->bf16 fused into one convert kernel (-2 launches).
// Props/MFMA mms unchanged from R10.

#define N_NODES 50000
#define N_EDGES 800000
#define NB_SCAN 196          // ceil(50000/256)
#define NBUCK   1563         // ceil(50000/32)

typedef __attribute__((ext_vector_type(8))) short bf16x8;
typedef __attribute__((ext_vector_type(4))) float f32x4;

__device__ inline ushort f2b(float x) {   // fp32 -> bf16 bits, RTNE
    unsigned u = __float_as_uint(x);
    return (ushort)((u + 0x7FFFu + ((u >> 16) & 1u)) >> 16);
}
__device__ inline float b2f(ushort b) { return __uint_as_float(((unsigned)b) << 16); }
__device__ inline float lo_f(unsigned u) { return __uint_as_float(u << 16); }
__device__ inline float hi_f(unsigned u) { return __uint_as_float(u & 0xFFFF0000u); }
__device__ inline unsigned pack2(float lo, float hi) {
    return ((unsigned)f2b(hi) << 16) | (unsigned)f2b(lo);
}

// ---------------- graph preprocessing ----------------

__global__ void count_deg_kernel(const int* __restrict__ col, int* __restrict__ deg, int e) {
    int i = blockIdx.x * 256 + threadIdx.x;
    if (i < e) atomicAdd(&deg[col[i]], 1);
}

__global__ void scan1_kernel(const int* __restrict__ deg, int* __restrict__ bsum,
                             float* __restrict__ dinv) {
    __shared__ int sd[256];
    int tid = threadIdx.x;
    int i = blockIdx.x * 256 + tid;
    int v = (i < N_NODES) ? deg[i] : 0;
    if (i < N_NODES) dinv[i] = (v > 0) ? (1.0f / sqrtf((float)v)) : 0.f;
    sd[tid] = v;
    __syncthreads();
    for (int o = 128; o > 0; o >>= 1) {
        if (tid < o) sd[tid] += sd[tid + o];
        __syncthreads();
    }
    if (tid == 0) bsum[blockIdx.x] = sd[0];
}

__global__ void scan2_kernel(int* __restrict__ bsum) {
    __shared__ int sd[256];
    int tid = threadIdx.x;
    int v = (tid < NB_SCAN) ? bsum[tid] : 0;
    sd[tid] = v;
    __syncthreads();
    for (int o = 1; o < 256; o <<= 1) {
        int t = (tid >= o) ? sd[tid - o] : 0;
        __syncthreads();
        sd[tid] += t;
        __syncthreads();
    }
    if (tid < NB_SCAN) bsum[tid] = sd[tid] - v;   // exclusive
}

// off[i]; also bucket cursors bcur[b] = off[b*32]
__global__ void scan3_kernel(const int* __restrict__ deg, const int* __restrict__ bsum,
                             int* __restrict__ off, int* __restrict__ bcur) {
    __shared__ int sd[256];
    int tid = threadIdx.x;
    int i = blockIdx.x * 256 + tid;
    int v = (i < N_NODES) ? deg[i] : 0;
    sd[tid] = v;
    __syncthreads();
    for (int o = 1; o < 256; o <<= 1) {
        int t = (tid >= o) ? sd[tid - o] : 0;
        __syncthreads();
        sd[tid] += t;
        __syncthreads();
    }
    if (i < N_NODES) {
        int val = bsum[blockIdx.x] + sd[tid] - v;
        off[i] = val;
        if ((i & 31) == 0) bcur[i >> 5] = val;
    }
    if (i == N_NODES - 1) off[N_NODES] = N_EDGES;
}

// binA: append packed (src,col) to bucket col>>5. Bucket regions == CSR ranges.
__global__ void bin_scatter_kernel(const int* __restrict__ row, const int* __restrict__ col,
                                   int* __restrict__ bcur, unsigned* __restrict__ binned,
                                   int e) {
    int i = blockIdx.x * 256 + threadIdx.x;
    if (i < e) {
        int r = row[i], c = col[i];
        int p = atomicAdd(&bcur[c >> 5], 1);
        binned[p] = ((unsigned)r << 16) | (unsigned)c;
    }
}

// binB: one block per bucket; LDS cursors; write final meta (hot 4KB region).
__global__ void csr_place_kernel(const unsigned* __restrict__ binned,
                                 const int* __restrict__ off,
                                 const float* __restrict__ dinv,
                                 int2* __restrict__ meta) {
    __shared__ int lcur[32];
    const int b = blockIdx.x;
    const int n0 = b * 32;
    const int nend = min(n0 + 32, N_NODES);
    const int tid = threadIdx.x;
    if (tid < 32) {
        int n = n0 + tid;
        lcur[tid] = (n < N_NODES) ? off[n] : 0;
    }
    __syncthreads();
    const int base = off[n0];
    const int cnt = off[nend] - base;
    for (int i = tid; i < cnt; i += 256) {
        unsigned ec = binned[base + i];
        int src = (int)(ec >> 16);
        int c = (int)(ec & 0xFFFFu);
        int p = atomicAdd(&lcur[c - n0], 1);
        float w = dinv[src] * dinv[c];
        meta[p] = make_int2(src, __float_as_int(w));
    }
}

// -------- fused conversions: W1->W1T, W2->W2T, x->xb (bf16) --------
// blocks [0,256): W1T; [256,384): W2T; [384,6634): xb
__global__ void convert_kernel(const float* __restrict__ W1, const float* __restrict__ W2,
                               const float* __restrict__ x, ushort* __restrict__ W1T,
                               ushort* __restrict__ W2T, ushort* __restrict__ xb) {
    int bid = blockIdx.x;
    if (bid < 256) {
        int idx = bid * 256 + threadIdx.x;          // [4][128c][128k]
        int k = idx & 127;
        int hc = idx >> 7;
        int c = hc & 127;
        int hop = hc >> 7;
        W1T[idx] = f2b(W1[(((size_t)hop * 128 + k) << 7) | c]);
    } else if (bid < 384) {
        int idx = (bid - 256) * 256 + threadIdx.x;  // [4][64c][128k]
        int k = idx & 127;
        int hc = idx >> 7;
        int c = hc & 63;
        int hop = hc >> 6;
        W2T[idx] = f2b(W2[(((size_t)hop * 128 + k) << 6) | c]);
    } else {
        int i = (bid - 384) * 256 + threadIdx.x;    // one float4 per thread
        float4 v = ((const float4*)x)[i];
        ushort4 bb;
        bb.x = f2b(v.x); bb.y = f2b(v.y); bb.z = f2b(v.z); bb.w = f2b(v.w);
        ((ushort4*)xb)[i] = bb;
    }
}

// -------- prop128b: bf16 rows (128 wide). 1 node / 64-lane wave, u32 (2 bf16)/lane.
__global__ void prop128b(const ushort* __restrict__ h, const int* __restrict__ off,
                         const int2* __restrict__ meta, ushort* __restrict__ out) {
    int node = blockIdx.x * 4 + (threadIdx.x >> 6);
    int lane = threadIdx.x & 63;
    int s = __builtin_amdgcn_readfirstlane(off[node]);
    int e = __builtin_amdgcn_readfirstlane(off[node + 1]);
    const unsigned* h2 = (const unsigned*)h;   // 64 u32 per row

    float accx[4] = {0.f, 0.f, 0.f, 0.f};
    float accy[4] = {0.f, 0.f, 0.f, 0.f};
    int j = s;
    for (; j + 15 < e; j += 16) {
        int2 m[16];
        unsigned v[16];
#pragma unroll
        for (int u = 0; u < 16; ++u) m[u] = meta[j + u];
#pragma unroll
        for (int u = 0; u < 16; ++u) v[u] = h2[(size_t)m[u].x * 64 + lane];
#pragma unroll
        for (int u = 0; u < 16; ++u) {
            float w = __int_as_float(m[u].y);
            accx[u & 3] += w * lo_f(v[u]);
            accy[u & 3] += w * hi_f(v[u]);
        }
    }
    for (; j + 3 < e; j += 4) {
        int2 m[4];
        unsigned v[4];
#pragma unroll
        for (int u = 0; u < 4; ++u) m[u] = meta[j + u];
#pragma unroll
        for (int u = 0; u < 4; ++u) v[u] = h2[(size_t)m[u].x * 64 + lane];
#pragma unroll
        for (int u = 0; u < 4; ++u) {
            float w = __int_as_float(m[u].y);
            accx[u] += w * lo_f(v[u]);
            accy[u] += w * hi_f(v[u]);
        }
    }
    for (; j < e; ++j) {
        int2 m = meta[j];
        unsigned v = h2[(size_t)m.x * 64 + lane];
        float w = __int_as_float(m.y);
        accx[0] += w * lo_f(v);
        accy[0] += w * hi_f(v);
    }
    float rx = (accx[0] + accx[1]) + (accx[2] + accx[3]);
    float ry = (accy[0] + accy[1]) + (accy[2] + accy[3]);
    ((unsigned*)out)[(size_t)node * 64 + lane] = pack2(rx, ry);
}

// -------- prop64b: bf16 64-wide rows (one line/edge). 1 node/wave, ushort/lane.
template <int EPI>   // 0 = accumulate+store bf16, 2 = +bias, log_softmax -> fp32 out
__global__ void prop64b(const ushort* __restrict__ h, const int* __restrict__ off,
                        const int2* __restrict__ meta, const ushort* __restrict__ yadd,
                        const float* __restrict__ bias, void* __restrict__ outp) {
    int node = blockIdx.x * 4 + (threadIdx.x >> 6);
    int lane = threadIdx.x & 63;
    int s = __builtin_amdgcn_readfirstlane(off[node]);
    int e = __builtin_amdgcn_readfirstlane(off[node + 1]);

    float yv = b2f(yadd[(size_t)node * 64 + lane]);

    float acc[4] = {0.f, 0.f, 0.f, 0.f};
    int j = s;
    for (; j + 15 < e; j += 16) {
        int2 m[16];
        ushort v[16];
#pragma unroll
        for (int u = 0; u < 16; ++u) m[u] = meta[j + u];
#pragma unroll
        for (int u = 0; u < 16; ++u) v[u] = h[(size_t)m[u].x * 64 + lane];
#pragma unroll
        for (int u = 0; u < 16; ++u) acc[u & 3] += __int_as_float(m[u].y) * b2f(v[u]);
    }
    for (; j + 3 < e; j += 4) {
        int2 m[4];
        ushort v[4];
#pragma unroll
        for (int u = 0; u < 4; ++u) m[u] = meta[j + u];
#pragma unroll
        for (int u = 0; u < 4; ++u) v[u] = h[(size_t)m[u].x * 64 + lane];
#pragma unroll
        for (int u = 0; u < 4; ++u) acc[u] += __int_as_float(m[u].y) * b2f(v[u]);
    }
    for (; j < e; ++j) {
        int2 m = meta[j];
        acc[0] += __int_as_float(m.y) * b2f(h[(size_t)m.x * 64 + lane]);
    }
    float v = (acc[0] + acc[1]) + (acc[2] + acc[3]) + yv;
    if (EPI == 0) {
        ((ushort*)outp)[(size_t)node * 64 + lane] = f2b(v);
    } else {
        v += bias[lane];
        float m = v;
        for (int d = 32; d > 0; d >>= 1) m = fmaxf(m, __shfl_xor(m, d));
        float su = expf(v - m);
        for (int d = 32; d > 0; d >>= 1) su += __shfl_xor(su, d);
        ((float*)outp)[(size_t)node * 64 + lane] = (v - m) - logf(su);
    }
}

// ---- stage one 32x128 bf16 tile -> LDS with 16B-chunk XOR swizzle ----
__device__ inline void stage_tile(ushort* hs, const ushort* hp, int row0, int tid) {
    const uint4* srcv = (const uint4*)(hp + (size_t)row0 * 128);
    for (int i = tid; i < 512; i += 256) {   // 32 rows x 16 chunks of 16B
        int r = i >> 4, c = i & 15;
        uint4 v = make_uint4(0, 0, 0, 0);
        if (row0 + r < N_NODES) v = srcv[i];
        int pc = c ^ (r & 7);
        *(uint4*)&hs[r * 128 + pc * 8] = v;
    }
}

// ---- mm_chain_mfma: hid = relu(sum_hop h_hop @ W1[hop] + b1), bf16 MFMA ----
__global__ __launch_bounds__(256) void mm_chain_mfma(
        const ushort* __restrict__ h0, const ushort* __restrict__ h1,
        const ushort* __restrict__ h2, const ushort* __restrict__ h3,
        const ushort* __restrict__ W1T,   // [4][128 cols][128 k] bf16
        const float* __restrict__ bias, ushort* __restrict__ outp) {
    __shared__ ushort hs[32 * 128];
    const int tid = threadIdx.x;
    const int w = tid >> 6;
    const int lane = tid & 63;
    const int lrow = lane & 15;
    const int kgrp = lane >> 4;
    const int row0 = blockIdx.x * 32;

    f32x4 acc[2][2] = {};   // [row-tile][col-tile]

#pragma unroll
    for (int hop = 0; hop < 4; ++hop) {
        const ushort* hp = (hop == 0) ? h0 : (hop == 1) ? h1 : (hop == 2) ? h2 : h3;
        if (hop) __syncthreads();
        stage_tile(hs, hp, row0, tid);
        __syncthreads();

#pragma unroll
        for (int kc = 0; kc < 4; ++kc) {
            bf16x8 a[2], b[2];
#pragma unroll
            for (int rt = 0; rt < 2; ++rt) {
                int row = rt * 16 + lrow;
                a[rt] = *(const bf16x8*)&hs[row * 128 + (((kc * 4 + kgrp) ^ (row & 7)) * 8)];
            }
#pragma unroll
            for (int ct = 0; ct < 2; ++ct) {
                int col = w * 32 + ct * 16 + lrow;
                b[ct] = *(const bf16x8*)&W1T[(((size_t)hop * 128 + col) << 7) + kc * 32 + kgrp * 8];
            }
#pragma unroll
            for (int rt = 0; rt < 2; ++rt)
#pragma unroll
                for (int ct = 0; ct < 2; ++ct)
                    acc[rt][ct] = __builtin_amdgcn_mfma_f32_16x16x32_bf16(
                        a[rt], b[ct], acc[rt][ct], 0, 0, 0);
        }
    }

#pragma unroll
    for (int rt = 0; rt < 2; ++rt)
#pragma unroll
        for (int ct = 0; ct < 2; ++ct) {
            int col = w * 32 + ct * 16 + lrow;
            float bv = bias[col];
#pragma unroll
            for (int i = 0; i < 4; ++i) {
                int row = row0 + rt * 16 + kgrp * 4 + i;
                if (row < N_NODES)
                    outp[(size_t)row * 128 + col] = f2b(fmaxf(acc[rt][ct][i] + bv, 0.f));
            }
        }
}

// ---- mm_y_mfma: y[hop] = hid @ W2[hop] for all 4 hops; wave w = hop ----
__global__ __launch_bounds__(256) void mm_y_mfma(
        const ushort* __restrict__ h,
        const ushort* __restrict__ W2T,   // [4][64 cols][128 k] bf16
        ushort* __restrict__ y) {         // [4][N][64] bf16
    __shared__ ushort hs[32 * 128];
    const int tid = threadIdx.x;
    const int w = tid >> 6;               // = hop
    const int lane = tid & 63;
    const int lrow = lane & 15;
    const int kgrp = lane >> 4;
    const int row0 = blockIdx.x * 32;

    f32x4 acc[2][4] = {};   // [row-tile][col-tile]

    stage_tile(hs, h, row0, tid);
    __syncthreads();

#pragma unroll
    for (int kc = 0; kc < 4; ++kc) {
        bf16x8 a[2], b[4];
#pragma unroll
        for (int rt = 0; rt < 2; ++rt) {
            int row = rt * 16 + lrow;
            a[rt] = *(const bf16x8*)&hs[row * 128 + (((kc * 4 + kgrp) ^ (row & 7)) * 8)];
        }
#pragma unroll
        for (int ct = 0; ct < 4; ++ct) {
            int col = ct * 16 + lrow;
            b[ct] = *(const bf16x8*)&W2T[(((size_t)w * 64 + col) << 7) + kc * 32 + kgrp * 8];
        }
#pragma unroll
        for (int rt = 0; rt < 2; ++rt)
#pragma unroll
            for (int ct = 0; ct < 4; ++ct)
                acc[rt][ct] = __builtin_amdgcn_mfma_f32_16x16x32_bf16(
                    a[rt], b[ct], acc[rt][ct], 0, 0, 0);
    }

    ushort* yp = y + (size_t)w * N_NODES * 64;
#pragma unroll
    for (int rt = 0; rt < 2; ++rt)
#pragma unroll
        for (int ct = 0; ct < 4; ++ct) {
            int col = ct * 16 + lrow;
#pragma unroll
            for (int i = 0; i < 4; ++i) {
                int row = row0 + rt * 16 + kgrp * 4 + i;
                if (row < N_NODES)
                    yp[(size_t)row * 64 + col] = f2b(acc[rt][ct][i]);
            }
        }
}

// ---------------- launch ----------------

extern "C" void kernel_launch(void* const* d_in, const int* in_sizes, int n_in,
                              void* d_out, int out_size, void* d_ws, size_t ws_size,
                              hipStream_t stream) {
    const float* x  = (const float*)d_in[0];
    const int*   ei = (const int*)d_in[1];
    const float* W1 = (const float*)d_in[2];
    const float* b1 = (const float*)d_in[3];
    const float* W2 = (const float*)d_in[4];
    const float* b2 = (const float*)d_in[5];
    float* out = (float*)d_out;

    const int* row = ei;             // edge_index[0]
    const int* col = ei + N_EDGES;   // edge_index[1]

    char* ws_base = (char*)d_ws;
    size_t o = 0;
    auto carve = [&](size_t bytes) {
        void* p = ws_base + o;
        o = (o + bytes + 511) & ~(size_t)511;
        return p;
    };
    int*      deg    = (int*)carve(N_NODES * 4);
    float*    dinv   = (float*)carve(N_NODES * 4);
    int*      off    = (int*)carve((N_NODES + 1) * 4);
    int*      bsum   = (int*)carve(NB_SCAN * 4);
    int*      bcur   = (int*)carve(NBUCK * 4);
    unsigned* binned = (unsigned*)carve((size_t)N_EDGES * 4);
    int2*     meta   = (int2*)carve((size_t)N_EDGES * 8);
    ushort*   W1T    = (ushort*)carve(4 * 128 * 128 * 2);
    ushort*   W2T    = (ushort*)carve(4 * 64 * 128 * 2);
    ushort*   xb     = (ushort*)carve((size_t)N_NODES * 128 * 2);
    ushort*   A      = (ushort*)carve((size_t)N_NODES * 128 * 2);
    ushort*   B      = (ushort*)carve((size_t)N_NODES * 128 * 2);
    ushort*   C      = (ushort*)carve((size_t)N_NODES * 128 * 2);
    ushort*   hid    = (ushort*)carve((size_t)N_NODES * 128 * 2);
    ushort*   y2     = (ushort*)carve((size_t)4 * N_NODES * 64 * 2);   // [4][N][64]
    ushort*   T2     = (ushort*)carve((size_t)N_NODES * 64 * 2);

    ushort* y2_0 = y2;
    ushort* y2_1 = y2 + (size_t)1 * N_NODES * 64;
    ushort* y2_2 = y2 + (size_t)2 * N_NODES * 64;
    ushort* y2_3 = y2 + (size_t)3 * N_NODES * 64;
    ushort* S2   = y2_3;   // reuse once y2_3 is consumed

    const int nb_e = (N_EDGES + 255) / 256;   // 3125

    // fused weight/feature conversions (independent of graph prep)
    convert_kernel<<<6634, 256, 0, stream>>>(W1, W2, x, W1T, W2T, xb);

    // graph preprocessing: degree -> scans -> binA -> binB
    hipMemsetAsync(deg, 0, N_NODES * 4, stream);
    count_deg_kernel<<<nb_e, 256, 0, stream>>>(col, deg, N_EDGES);
    scan1_kernel<<<NB_SCAN, 256, 0, stream>>>(deg, bsum, dinv);
    scan2_kernel<<<1, 256, 0, stream>>>(bsum);
    scan3_kernel<<<NB_SCAN, 256, 0, stream>>>(deg, bsum, off, bcur);
    bin_scatter_kernel<<<nb_e, 256, 0, stream>>>(row, col, bcur, binned, N_EDGES);
    csr_place_kernel<<<NBUCK, 256, 0, stream>>>(binned, off, dinv, meta);

    // ----- layer 1: chain props (bf16), then one fused K=512 MFMA matmul -> hid (bf16)
    prop128b<<<12500, 256, 0, stream>>>(xb, off, meta, A);
    prop128b<<<12500, 256, 0, stream>>>(A,  off, meta, B);
    prop128b<<<12500, 256, 0, stream>>>(B,  off, meta, C);
    mm_chain_mfma<<<1563, 256, 0, stream>>>(xb, A, B, C, W1T, b1, hid);

    // ----- layer 2 (Horner): out = log_softmax(z0 + A(z1 + A(z2 + A z3)) + b2)
    mm_y_mfma<<<1563, 256, 0, stream>>>(hid, W2T, y2);
    prop64b<0><<<12500, 256, 0, stream>>>(y2_3, off, meta, y2_2, nullptr, T2);
    prop64b<0><<<12500, 256, 0, stream>>>(T2,   off, meta, y2_1, nullptr, S2);
    prop64b<2><<<12500, 256, 0, stream>>>(S2,   off, meta, y2_0, b2,      out);
}